// Round 8
// baseline (120.526 us; speedup 1.0000x reference)
//
#include <hip/hip_runtime.h>

#define Bsz 64
#define Nn  256
#define Ee  20   // atom embedding dim
#define Dd  25   // gaussian centers
#define NBLK 1024  // 1024 blocks x 4 waves x 4 rows = 16384 (b,i) rows

using short8  = __attribute__((ext_vector_type(8))) short;  // 8 bf16 (4 VGPRs)
using floatx4 = __attribute__((ext_vector_type(4))) float;  // 4 fp32 acc
using float2v = __attribute__((ext_vector_type(2))) float;  // pk-f32 pair

#if __has_builtin(__builtin_amdgcn_exp2f)
#define EXP2F(x) __builtin_amdgcn_exp2f(x)
#else
#define EXP2F(x) __expf(0.6931471805599453f * (x))
#endif
#if __has_builtin(__builtin_amdgcn_rcpf)
#define RCPF(x) __builtin_amdgcn_rcpf(x)
#else
#define RCPF(x) (1.0f / (x))
#endif

__device__ __forceinline__ short f2bf(float x) {            // RNE fp32->bf16
    unsigned u = __float_as_uint(x);
    unsigned r = (u + 0x7FFFu + ((u >> 16) & 1u)) >> 16;
    return (short)r;
}
__device__ __forceinline__ float bf2f(short h) {
    return __uint_as_float(((unsigned)(unsigned short)h) << 16);
}
__device__ __forceinline__ float tanhfast(float x) {
    float e = __expf(2.0f * x);
    return 1.0f - 2.0f / (e + 1.0f);
}
// pack two fp32 -> two bf16 in one VALU op (RNE). dst.lo=cvt(a), dst.hi=cvt(b)
__device__ __forceinline__ unsigned packbf(float a, float b) {
    unsigned r;
    asm("v_cvt_pk_bf16_f32 %0, %1, %2" : "=v"(r) : "v"(a), "v"(b));
    return r;
}
// packed fma on row-pairs
__device__ __forceinline__ float2v pkfma(float2v a, float2v b, float2v c) {
    return __builtin_elementwise_fma(a, b, c);
}

// Tail compaction: valid tail data = regs 0..3 at lanes c16<4.
// 3x update_dpp(row_shr:4m, bank_mask 1<<m) -> lane L holds element
// (jsub=4*(L>>4)+((L>>2)&3), o=16+(L&3)); bijective. Returns 2^x (no +1).
__device__ __forceinline__ float tailE(floatx4 p) {
    int r = __float_as_int(p[0]);
    r = __builtin_amdgcn_update_dpp(r, __float_as_int(p[1]), 0x114, 0xF, 0x2, false);
    r = __builtin_amdgcn_update_dpp(r, __float_as_int(p[2]), 0x118, 0xF, 0x4, false);
    r = __builtin_amdgcn_update_dpp(r, __float_as_int(p[3]), 0x11C, 0xF, 0x8, false);
    return EXP2F(__int_as_float(r));
}

// gaussian fragment production for one j-tile, both rows of a pair packed.
// d2 = {d_rowA, d_rowB}; outputs bf16x8 fragments FA (rowA), FB (rowB).
__device__ __forceinline__ void mkfrags(float2v d2, float mu0,
                                        short8& FA, short8& FB) {
    const float Kc  = 2.8853900817779268f;            // 2*log2(e)
    const float T04 = 1.1541560327111707f;            // 0.4*Kc
    const float2v u2 = d2 - mu0;
    const float2v aG = (u2 * (-Kc)) * u2;
    const float2v aT = u2 * T04;
    const float2v g0 = {EXP2F(aG.x), EXP2F(aG.y)};
    const float2v tp = {EXP2F(aT.x), EXP2F(aT.y)};
    // packed serial power ladder: x_k = g0 * tp^k (c_k folded into weights)
    const float2v x1 = g0 * tp;
    const float2v x2 = x1 * tp;
    const float2v x3 = x2 * tp;
    const float2v x4 = x3 * tp;
    const float2v x5 = x4 * tp;
    const float2v x6 = x5 * tp;
    const float2v x7 = x6 * tp;
    union { short8 s; unsigned u4[4]; } U;
    U.u4[0] = packbf(g0.x, x1.x); U.u4[1] = packbf(x2.x, x3.x);
    U.u4[2] = packbf(x4.x, x5.x); U.u4[3] = packbf(x6.x, x7.x);
    FA = U.s;
    U.u4[0] = packbf(g0.y, x1.y); U.u4[1] = packbf(x2.y, x3.y);
    U.u4[2] = packbf(x4.y, x5.y); U.u4[3] = packbf(x6.y, x7.y);
    FB = U.s;
}

// Main kernel. Each wave owns 4 rows (b,i0..i0+3); 4 waves/block share b.
// Two row-pairs run the PROVEN R4 math verbatim (Kc-folded sigma path);
// per-wave prologue work (weight fragments, Vw gather loads, uo) is
// amortized over 4 rows instead of 2.
__global__ __launch_bounds__(256, 4) void dtnn_main(
    const int*   __restrict__ z,     // [B,N]
    const float* __restrict__ dist,  // [B,N,N]
    const float* __restrict__ emb,   // [N,E]
    const float* __restrict__ Vw,    // [E,45]
    const float* __restrict__ Vb,    // [E]
    const float* __restrict__ W1,    // [10,E]
    const float* __restrict__ W2,    // [1,10]
    float*       __restrict__ part)  // [NBLK]
{
    const int tid  = threadIdx.x;
    const int lane = tid & 63;
    const int wave = tid >> 6;
    const int blk  = blockIdx.x;
    const int b    = blk >> 4;                       // 16 blocks per batch
    const int i0   = ((blk & 15) << 4) | (wave << 2);// rows i0..i0+3

    const int c16  = lane & 15;
    const int quad = lane >> 4;
    const int k0   = quad * 8;
    const float Kc = 2.8853900817779268f;            // 2*log2(e)

    // wave-private LDS: rows 0/1 interleaved at [0..511], rows 2/3 at [512..]
    __shared__ float sD[4][4 * 256];
    float* sDw = sD[wave];

    // 16 coalesced row loads issued FIRST; latency hides under weight prologue
    const float* dr0 = dist + ((size_t)b * Nn + i0) * Nn;
    const float r0a = dr0[lane],          r0b = dr0[lane + 64];
    const float r0c = dr0[lane + 128],    r0d = dr0[lane + 192];
    const float r1a = dr0[Nn + lane],     r1b = dr0[Nn + lane + 64];
    const float r1c = dr0[Nn + lane+128], r1d = dr0[Nn + lane + 192];
    const float r2a = dr0[2*Nn + lane],     r2b = dr0[2*Nn + lane + 64];
    const float r2c = dr0[2*Nn + lane+128], r2d = dr0[2*Nn + lane + 192];
    const float r3a = dr0[3*Nn + lane],     r3b = dr0[3*Nn + lane + 64];
    const float r3c = dr0[3*Nn + lane+128], r3d = dr0[3*Nn + lane + 192];

    const int zu0 = __builtin_amdgcn_readfirstlane(z[b * Nn + i0]);
    const int zu1 = __builtin_amdgcn_readfirstlane(z[b * Nn + i0 + 1]);
    const int zu2 = __builtin_amdgcn_readfirstlane(z[b * Nn + i0 + 2]);
    const int zu3 = __builtin_amdgcn_readfirstlane(z[b * Nn + i0 + 3]);
    const float m0 = (zu0 != 0) ? 1.0f : 0.0f;
    const float m1 = (zu1 != 0) ? 1.0f : 0.0f;
    const float m2 = (zu2 != 0) ? 1.0f : 0.0f;
    const float m3 = (zu3 != 0) ? 1.0f : 0.0f;

    // Gaussian step constants c_jj = e^{-0.08 jj^2}, folded into the weights.
    const float cj[8] = {1.0f, 0.9231163463866358f, 0.7261490370736909f,
                         0.48675225595997157f, 0.2780373004531941f,
                         0.1353352832366127f, 0.05613476283303940f,
                         0.019841459768337877f};

    // weight fragments (per-wave; amortized over 4 rows) + per-row biases
    short8 whiK[2], wloK[2];
    floatx4 bias0[2], bias1[2], bias2[2], bias3[2];
    #pragma unroll
    for (int nt = 0; nt < 2; ++nt) {
        const int o = nt * 16 + c16;
        const bool valid = (o < Ee);
        const int oc = valid ? o : 0;                 // clamp vs OOB speculation
        #pragma unroll
        for (int jj = 0; jj < 8; ++jj) {
            const int k = k0 + jj;
            const float v = (valid && k < Dd)
                          ? Kc * cj[jj] * Vw[oc * 45 + 20 + k] : 0.0f;
            const short h = f2bf(v);
            whiK[nt][jj] = h;
            wloK[nt][jj] = f2bf(v - bf2f(h));
        }
        // A[o] = Kc*(Vb[o] + m * Vw[o,:20].emb[z]) ; Vw load shared by 4 rows
        float d0 = 0.0f, d1 = 0.0f, d2 = 0.0f, d3 = 0.0f;
        #pragma unroll
        for (int f = 0; f < Ee; ++f) {
            const float w = valid ? Vw[oc * 45 + f] : 0.0f;
            d0 = fmaf(w, emb[zu0 * Ee + f], d0);   // emb: s_loads (uniform)
            d1 = fmaf(w, emb[zu1 * Ee + f], d1);
            d2 = fmaf(w, emb[zu2 * Ee + f], d2);
            d3 = fmaf(w, emb[zu3 * Ee + f], d3);
        }
        const float vb = valid ? Vb[oc] : 0.0f;
        const float A0 = Kc * (vb + m0 * d0);
        const float A1 = Kc * (vb + m1 * d1);
        const float A2 = Kc * (vb + m2 * d2);
        const float A3 = Kc * (vb + m3 * d3);
        bias0[nt] = (floatx4){A0, A0, A0, A0};
        bias1[nt] = (floatx4){A1, A1, A1, A1};
        bias2[nt] = (floatx4){A2, A2, A2, A2};
        bias3[nt] = (floatx4){A3, A3, A3, A3};
    }

    // stage rows into wave-private LDS as interleaved pairs (8x ds_write_b64)
    *(float2v*)&sDw[2 * lane]         = (float2v){r0a, r1a};
    *(float2v*)&sDw[2 * (lane + 64)]  = (float2v){r0b, r1b};
    *(float2v*)&sDw[2 * (lane + 128)] = (float2v){r0c, r1c};
    *(float2v*)&sDw[2 * (lane + 192)] = (float2v){r0d, r1d};
    *(float2v*)&sDw[512 + 2 * lane]         = (float2v){r2a, r3a};
    *(float2v*)&sDw[512 + 2 * (lane + 64)]  = (float2v){r2b, r3b};
    *(float2v*)&sDw[512 + 2 * (lane + 128)] = (float2v){r2c, r3c};
    *(float2v*)&sDw[512 + 2 * (lane + 192)] = (float2v){r2d, r3d};

    // ---- main loop: 16 j-tiles x 2 row-pairs (R4 math verbatim per pair)
    const float mu0 = 0.2f * (float)k0;
    float2v RmA = {0.0f, 0.0f}, RtA = {0.0f, 0.0f};  // rows 0/1
    float2v RmB = {0.0f, 0.0f}, RtB = {0.0f, 0.0f};  // rows 2/3

    #pragma unroll
    for (int t = 0; t < 16; ++t) {
        const float2v d01 = *(const float2v*)&sDw[2 * (16 * t + c16)];
        const float2v d23 = *(const float2v*)&sDw[512 + 2 * (16 * t + c16)];

        short8 GA, GB, GC, GD;
        mkfrags(d01, mu0, GA, GB);
        mkfrags(d23, mu0, GC, GD);

        // pair 0/1: 8 MFMAs, bias as C operand
        floatx4 p00 = __builtin_amdgcn_mfma_f32_16x16x32_bf16(GA, whiK[0], bias0[0], 0, 0, 0);
        p00 = __builtin_amdgcn_mfma_f32_16x16x32_bf16(GA, wloK[0], p00, 0, 0, 0);
        floatx4 p01 = __builtin_amdgcn_mfma_f32_16x16x32_bf16(GA, whiK[1], bias0[1], 0, 0, 0);
        p01 = __builtin_amdgcn_mfma_f32_16x16x32_bf16(GA, wloK[1], p01, 0, 0, 0);
        floatx4 p10 = __builtin_amdgcn_mfma_f32_16x16x32_bf16(GB, whiK[0], bias1[0], 0, 0, 0);
        p10 = __builtin_amdgcn_mfma_f32_16x16x32_bf16(GB, wloK[0], p10, 0, 0, 0);
        floatx4 p11 = __builtin_amdgcn_mfma_f32_16x16x32_bf16(GB, whiK[1], bias1[1], 0, 0, 0);
        p11 = __builtin_amdgcn_mfma_f32_16x16x32_bf16(GB, wloK[1], p11, 0, 0, 0);

        // pair 2/3: 8 MFMAs
        floatx4 s00 = __builtin_amdgcn_mfma_f32_16x16x32_bf16(GC, whiK[0], bias2[0], 0, 0, 0);
        s00 = __builtin_amdgcn_mfma_f32_16x16x32_bf16(GC, wloK[0], s00, 0, 0, 0);
        floatx4 s01 = __builtin_amdgcn_mfma_f32_16x16x32_bf16(GC, whiK[1], bias2[1], 0, 0, 0);
        s01 = __builtin_amdgcn_mfma_f32_16x16x32_bf16(GC, wloK[1], s01, 0, 0, 0);
        floatx4 s10 = __builtin_amdgcn_mfma_f32_16x16x32_bf16(GD, whiK[0], bias3[0], 0, 0, 0);
        s10 = __builtin_amdgcn_mfma_f32_16x16x32_bf16(GD, wloK[0], s10, 0, 0, 0);
        floatx4 s11 = __builtin_amdgcn_mfma_f32_16x16x32_bf16(GD, whiK[1], bias3[1], 0, 0, 0);
        s11 = __builtin_amdgcn_mfma_f32_16x16x32_bf16(GD, wloK[1], s11, 0, 0, 0);

        // sigma combine pair 0/1: A_i = 2^p_i + 1, rational 4-way + tail
        {
            float2v A0 = {EXP2F(p00[0]), EXP2F(p10[0])};
            float2v A1 = {EXP2F(p00[1]), EXP2F(p10[1])};
            float2v A2 = {EXP2F(p00[2]), EXP2F(p10[2])};
            float2v A3 = {EXP2F(p00[3]), EXP2F(p10[3])};
            A0 += 1.0f; A1 += 1.0f; A2 += 1.0f; A3 += 1.0f;
            const float2v q01 = A0 * A1, q23 = A2 * A3;
            const float2v n4 = pkfma(q01, A2 + A3, q23 * (A0 + A1));
            const float2v d4 = q01 * q23;
            float2v At2 = {tailE(p01), tailE(p11)};
            At2 += 1.0f;
            const float2v Da = d4 * At2;
            const float inv = RCPF(Da.x * Da.y);
            const float2v inv2 = {inv * Da.y, inv * Da.x};
            RmA = pkfma(n4 * At2, inv2, RmA);
            RtA = pkfma(d4, inv2, RtA);
        }
        // sigma combine pair 2/3
        {
            float2v A0 = {EXP2F(s00[0]), EXP2F(s10[0])};
            float2v A1 = {EXP2F(s00[1]), EXP2F(s10[1])};
            float2v A2 = {EXP2F(s00[2]), EXP2F(s10[2])};
            float2v A3 = {EXP2F(s00[3]), EXP2F(s10[3])};
            A0 += 1.0f; A1 += 1.0f; A2 += 1.0f; A3 += 1.0f;
            const float2v q01 = A0 * A1, q23 = A2 * A3;
            const float2v n4 = pkfma(q01, A2 + A3, q23 * (A0 + A1));
            const float2v d4 = q01 * q23;
            float2v At2 = {tailE(s01), tailE(s11)};
            At2 += 1.0f;
            const float2v Da = d4 * At2;
            const float inv = RCPF(Da.x * Da.y);
            const float2v inv2 = {inv * Da.y, inv * Da.x};
            RmB = pkfma(n4 * At2, inv2, RmB);
            RtB = pkfma(d4, inv2, RtB);
        }
    }

    // unpack rows, reduce (main: quads; tail: all lanes sharing lane&3)
    float Rm0 = RmA.x, Rm1 = RmA.y, Rm2 = RmB.x, Rm3 = RmB.y;
    float Rt0 = RtA.x, Rt1 = RtA.y, Rt2 = RtB.x, Rt3 = RtB.y;
    Rm0 += __shfl_xor(Rm0, 16, 64);  Rm0 += __shfl_xor(Rm0, 32, 64);
    Rm1 += __shfl_xor(Rm1, 16, 64);  Rm1 += __shfl_xor(Rm1, 32, 64);
    Rm2 += __shfl_xor(Rm2, 16, 64);  Rm2 += __shfl_xor(Rm2, 32, 64);
    Rm3 += __shfl_xor(Rm3, 16, 64);  Rm3 += __shfl_xor(Rm3, 32, 64);
    Rt0 += __shfl_xor(Rt0, 4, 64);   Rt0 += __shfl_xor(Rt0, 8, 64);
    Rt0 += __shfl_xor(Rt0, 16, 64);  Rt0 += __shfl_xor(Rt0, 32, 64);
    Rt1 += __shfl_xor(Rt1, 4, 64);   Rt1 += __shfl_xor(Rt1, 8, 64);
    Rt1 += __shfl_xor(Rt1, 16, 64);  Rt1 += __shfl_xor(Rt1, 32, 64);
    Rt2 += __shfl_xor(Rt2, 4, 64);   Rt2 += __shfl_xor(Rt2, 8, 64);
    Rt2 += __shfl_xor(Rt2, 16, 64);  Rt2 += __shfl_xor(Rt2, 32, 64);
    Rt3 += __shfl_xor(Rt3, 4, 64);   Rt3 += __shfl_xor(Rt3, 8, 64);
    Rt3 += __shfl_xor(Rt3, 16, 64);  Rt3 += __shfl_xor(Rt3, 32, 64);

    // folded top-MLP coefficients (channels 0..15 at c16; 16..19 at lane&3)
    const int om = c16;              // always < Ee
    const int ot = 16 + (lane & 3);  // always < Ee
    float uom = 0.0f, uot = 0.0f;
    #pragma unroll
    for (int p = 0; p < 10; ++p) {
        uom = fmaf(W2[p], W1[p * Ee + om], uom);
        uot = fmaf(W2[p], W1[p * Ee + ot], uot);
    }
    const float cfm0 = m0 * emb[zu0 * Ee + om];
    const float cfm1 = m1 * emb[zu1 * Ee + om];
    const float cfm2 = m2 * emb[zu2 * Ee + om];
    const float cfm3 = m3 * emb[zu3 * Ee + om];
    const float cft0 = m0 * emb[zu0 * Ee + ot];
    const float cft1 = m1 * emb[zu1 * Ee + ot];
    const float cft2 = m2 * emb[zu2 * Ee + ot];
    const float cft3 = m3 * emb[zu3 * Ee + ot];

    // epilogue: th = tanh(cf + m*(256 - 2R)); e = sum_o u[o]*th[o].
    // Tail terms appear 4x per 16-lane reduction group -> scale 0.25.
    const float ut4 = 0.25f * uot;
    float e = 0.0f;
    e = fmaf(tanhfast(cfm0 + m0 * (256.0f - 2.0f * Rm0)), uom, e);
    e = fmaf(tanhfast(cfm1 + m1 * (256.0f - 2.0f * Rm1)), uom, e);
    e = fmaf(tanhfast(cfm2 + m2 * (256.0f - 2.0f * Rm2)), uom, e);
    e = fmaf(tanhfast(cfm3 + m3 * (256.0f - 2.0f * Rm3)), uom, e);
    e = fmaf(tanhfast(cft0 + m0 * (256.0f - 2.0f * Rt0)), ut4, e);
    e = fmaf(tanhfast(cft1 + m1 * (256.0f - 2.0f * Rt1)), ut4, e);
    e = fmaf(tanhfast(cft2 + m2 * (256.0f - 2.0f * Rt2)), ut4, e);
    e = fmaf(tanhfast(cft3 + m3 * (256.0f - 2.0f * Rt3)), ut4, e);
    e += __shfl_xor(e, 1, 64);
    e += __shfl_xor(e, 2, 64);
    e += __shfl_xor(e, 4, 64);
    e += __shfl_xor(e, 8, 64);

    // block reduce: 4 waves -> one plain store (NO atomics)
    __shared__ float sE[4];
    if (lane == 0) sE[wave] = e;
    __syncthreads();
    if (tid == 0)
        part[blk] = sE[0] + sE[1] + sE[2] + sE[3];
}

// 64 blocks x 64 lanes: out[b] = sum of 16 block-partials + 256*C0
__global__ __launch_bounds__(64) void dtnn_reduce(
    const float* __restrict__ part,
    const float* __restrict__ b1, const float* __restrict__ W2,
    const float* __restrict__ b2, float* __restrict__ out)
{
    const int b = blockIdx.x;
    const int t = threadIdx.x;
    float v = (t < 16) ? part[b * 16 + t] : 0.0f;
    v += __shfl_xor(v, 1, 64);
    v += __shfl_xor(v, 2, 64);
    v += __shfl_xor(v, 4, 64);
    v += __shfl_xor(v, 8, 64);
    if (t == 0) {
        float c0 = b2[0];
        #pragma unroll
        for (int p = 0; p < 10; ++p) c0 = fmaf(W2[p], b1[p], c0);
        out[b] = v + 256.0f * c0;
    }
}

extern "C" void kernel_launch(void* const* d_in, const int* in_sizes, int n_in,
                              void* d_out, int out_size, void* d_ws, size_t ws_size,
                              hipStream_t stream) {
    const int*   z    = (const int*)  d_in[0];
    const float* dist = (const float*)d_in[1];
    const float* emb  = (const float*)d_in[2];
    const float* Vw   = (const float*)d_in[3];
    const float* Vb   = (const float*)d_in[4];
    const float* W1   = (const float*)d_in[5];
    const float* b1   = (const float*)d_in[6];
    const float* W2   = (const float*)d_in[7];
    const float* b2   = (const float*)d_in[8];
    float* out = (float*)d_out;

    float* partP = (float*)d_ws;   // [NBLK]

    // 2 dispatches: fat main (4 rows/wave, self-contained) + tiny reduce
    dtnn_main<<<NBLK, 256, 0, stream>>>(z, dist, emb, Vw, Vb, W1, W2, partP);
    dtnn_reduce<<<Bsz, 64, 0, stream>>>(partP, b1, W2, b2, out);
}

// Round 9
// 110.029 us; speedup vs baseline: 1.0954x; 1.0954x over previous
//
#include <hip/hip_runtime.h>

#define Bsz 64
#define Nn  256
#define Ee  20   // atom embedding dim
#define Dd  25   // gaussian centers
#define NBLK 2048  // 2048 blocks x 4 waves x 2 rows = 16384 (b,i) rows

using short8  = __attribute__((ext_vector_type(8))) short;  // 8 bf16 (4 VGPRs)
using floatx4 = __attribute__((ext_vector_type(4))) float;  // 4 fp32 acc
using float2v = __attribute__((ext_vector_type(2))) float;  // pk-f32 pair

#if __has_builtin(__builtin_amdgcn_exp2f)
#define EXP2F(x) __builtin_amdgcn_exp2f(x)
#else
#define EXP2F(x) __expf(0.6931471805599453f * (x))
#endif
#if __has_builtin(__builtin_amdgcn_rcpf)
#define RCPF(x) __builtin_amdgcn_rcpf(x)
#else
#define RCPF(x) (1.0f / (x))
#endif

__device__ __forceinline__ short f2bf(float x) {            // RNE fp32->bf16
    unsigned u = __float_as_uint(x);
    unsigned r = (u + 0x7FFFu + ((u >> 16) & 1u)) >> 16;
    return (short)r;
}
__device__ __forceinline__ float bf2f(short h) {
    return __uint_as_float(((unsigned)(unsigned short)h) << 16);
}
__device__ __forceinline__ float tanhfast(float x) {
    float e = __expf(2.0f * x);
    return 1.0f - 2.0f / (e + 1.0f);
}
// pack two fp32 -> two bf16 in one VALU op (RNE). dst.lo=cvt(a), dst.hi=cvt(b)
__device__ __forceinline__ unsigned packbf(float a, float b) {
    unsigned r;
    asm("v_cvt_pk_bf16_f32 %0, %1, %2" : "=v"(r) : "v"(a), "v"(b));
    return r;
}
// packed fma on row-pairs
__device__ __forceinline__ float2v pkfma(float2v a, float2v b, float2v c) {
    return __builtin_elementwise_fma(a, b, c);
}

// Tail compaction: valid tail data = regs 0..3 at lanes c16<4.
// 3x update_dpp(row_shr:4m, bank_mask 1<<m) -> lane L holds element
// (jsub=4*(L>>4)+((L>>2)&3), o=16+(L&3)); bijective. Returns 2^x (no +1).
__device__ __forceinline__ float tailE(floatx4 p) {
    int r = __float_as_int(p[0]);
    r = __builtin_amdgcn_update_dpp(r, __float_as_int(p[1]), 0x114, 0xF, 0x2, false);
    r = __builtin_amdgcn_update_dpp(r, __float_as_int(p[2]), 0x118, 0xF, 0x4, false);
    r = __builtin_amdgcn_update_dpp(r, __float_as_int(p[3]), 0x11C, 0xF, 0x8, false);
    return EXP2F(__int_as_float(r));
}

// Main kernel. Each wave owns 2 rows (b,i0),(b,i0+1); 4 waves/block share b.
// Rows PAIRED through the whole scalar path via packed-f32 (v_pk_*_f32):
// LDS holds interleaved {row0[j],row1[j]} so ds_read_b64 yields the pair.
__global__ __launch_bounds__(256, 4) void dtnn_main(
    const int*   __restrict__ z,     // [B,N]
    const float* __restrict__ dist,  // [B,N,N]
    const float* __restrict__ emb,   // [N,E]
    const float* __restrict__ Vw,    // [E,45]
    const float* __restrict__ Vb,    // [E]
    const float* __restrict__ W1,    // [10,E]
    const float* __restrict__ W2,    // [1,10]
    float*       __restrict__ part)  // [NBLK]
{
    const int tid  = threadIdx.x;
    const int lane = tid & 63;
    const int wave = tid >> 6;
    const int blk  = blockIdx.x;
    const int b    = blk >> 5;                       // 32 blocks per batch
    const int i0   = ((blk & 31) << 3) | (wave << 1);// rows i0, i0+1

    const int c16  = lane & 15;
    const int quad = lane >> 4;
    const int k0   = quad * 8;
    const float Kc = 2.8853900817779268f;            // 2*log2(e)
    const float T04 = 1.1541560327111707f;           // 0.4*Kc

    // wave-private LDS, interleaved row pair: sDw[2*j]=row0[j], [2*j+1]=row1[j]
    __shared__ float sD[4][2 * 256];
    float* sDw = sD[wave];

    // 8 coalesced row loads issued FIRST; latency hides under weight prologue
    const float* dr0 = dist + ((size_t)b * Nn + i0) * Nn;
    const float a0r = dr0[lane],        a1r = dr0[lane + 64];
    const float a2r = dr0[lane + 128],  a3r = dr0[lane + 192];
    const float b0r = dr0[Nn + lane],       b1r = dr0[Nn + lane + 64];
    const float b2r = dr0[Nn + lane + 128], b3r = dr0[Nn + lane + 192];

    const int zi0 = z[b * Nn + i0];
    const int zi1 = z[b * Nn + i0 + 1];
    const int zu0 = __builtin_amdgcn_readfirstlane(zi0);  // wave-uniform
    const int zu1 = __builtin_amdgcn_readfirstlane(zi1);
    const float m0 = (zu0 != 0) ? 1.0f : 0.0f;
    const float m1 = (zu1 != 0) ? 1.0f : 0.0f;

    // Gaussian step constants c_jj = e^{-0.08 jj^2}, folded into the weights.
    const float cj[8] = {1.0f, 0.9231163463866358f, 0.7261490370736909f,
                         0.48675225595997157f, 0.2780373004531941f,
                         0.1353352832366127f, 0.05613476283303940f,
                         0.019841459768337877f};

    // weight fragments (divergent gathers; L1-hot) + per-row bias
    short8 whiK[2], wloK[2];
    floatx4 bias0[2], bias1[2];
    #pragma unroll
    for (int nt = 0; nt < 2; ++nt) {
        const int o = nt * 16 + c16;
        const bool valid = (o < Ee);
        const int oc = valid ? o : 0;                 // clamp vs OOB speculation
        #pragma unroll
        for (int jj = 0; jj < 8; ++jj) {
            const int k = k0 + jj;
            const float v = (valid && k < Dd)
                          ? Kc * cj[jj] * Vw[oc * 45 + 20 + k] : 0.0f;
            const short h = f2bf(v);
            whiK[nt][jj] = h;
            wloK[nt][jj] = f2bf(v - bf2f(h));
        }
        // A[o] = Kc*(Vb[o] + m * Vw[o,:20].emb[z])
        float dot0 = 0.0f, dot1 = 0.0f;
        #pragma unroll
        for (int f = 0; f < Ee; ++f) {
            const float w = valid ? Vw[oc * 45 + f] : 0.0f;
            dot0 = fmaf(w, emb[zu0 * Ee + f], dot0);   // emb: s_loads (uniform)
            dot1 = fmaf(w, emb[zu1 * Ee + f], dot1);
        }
        const float vb = valid ? Vb[oc] : 0.0f;
        const float A0 = Kc * (vb + m0 * dot0);
        const float A1 = Kc * (vb + m1 * dot1);
        bias0[nt] = (floatx4){A0, A0, A0, A0};
        bias1[nt] = (floatx4){A1, A1, A1, A1};
    }

    // stage rows into wave-private LDS as interleaved pairs (4x ds_write_b64)
    *(float2v*)&sDw[2 * lane]         = (float2v){a0r, b0r};
    *(float2v*)&sDw[2 * (lane + 64)]  = (float2v){a1r, b1r};
    *(float2v*)&sDw[2 * (lane + 128)] = (float2v){a2r, b2r};
    *(float2v*)&sDw[2 * (lane + 192)] = (float2v){a3r, b3r};

    // ---- main loop: 16 j-tiles; rows packed as float2 {row0,row1}
    const float mu0 = 0.2f * (float)k0;
    float2v Rm2 = {0.0f, 0.0f};     // main channels (c16), per-row in .x/.y
    float2v Rt2 = {0.0f, 0.0f};     // tail channels (16+(lane&3))

    #pragma unroll
    for (int t = 0; t < 16; ++t) {
        // one ds_read_b64: {d_row0, d_row1}, 4-lane same-address broadcast
        const float2v d2 = *(const float2v*)&sDw[2 * (16 * t + c16)];

        // gaussian args (packed): g0 = 2^(-Kc u^2), tp = 2^(0.4*Kc u)
        const float2v u2 = d2 - mu0;
        const float2v aG = (u2 * (-Kc)) * u2;
        const float2v aT = u2 * T04;
        const float2v g0 = {EXP2F(aG.x), EXP2F(aG.y)};
        const float2v tp = {EXP2F(aT.x), EXP2F(aT.y)};

        // packed serial power ladder: x_k = g0 * tp^k (c_k folded into weights)
        const float2v x1 = g0 * tp;
        const float2v x2 = x1 * tp;
        const float2v x3 = x2 * tp;
        const float2v x4 = x3 * tp;
        const float2v x5 = x4 * tp;
        const float2v x6 = x5 * tp;
        const float2v x7 = x6 * tp;

        short8 GA, GB;
        {
            union { short8 s; unsigned u4[4]; } U;
            U.u4[0] = packbf(g0.x, x1.x); U.u4[1] = packbf(x2.x, x3.x);
            U.u4[2] = packbf(x4.x, x5.x); U.u4[3] = packbf(x6.x, x7.x);
            GA = U.s;
            U.u4[0] = packbf(g0.y, x1.y); U.u4[1] = packbf(x2.y, x3.y);
            U.u4[2] = packbf(x4.y, x5.y); U.u4[3] = packbf(x6.y, x7.y);
            GB = U.s;
        }

        // 8 MFMAs (2 rows x 2 ntiles x hi/lo), bias as C operand
        floatx4 p00 = __builtin_amdgcn_mfma_f32_16x16x32_bf16(GA, whiK[0], bias0[0], 0, 0, 0);
        p00 = __builtin_amdgcn_mfma_f32_16x16x32_bf16(GA, wloK[0], p00, 0, 0, 0);
        floatx4 p01 = __builtin_amdgcn_mfma_f32_16x16x32_bf16(GA, whiK[1], bias0[1], 0, 0, 0);
        p01 = __builtin_amdgcn_mfma_f32_16x16x32_bf16(GA, wloK[1], p01, 0, 0, 0);
        floatx4 p10 = __builtin_amdgcn_mfma_f32_16x16x32_bf16(GB, whiK[0], bias1[0], 0, 0, 0);
        p10 = __builtin_amdgcn_mfma_f32_16x16x32_bf16(GB, wloK[0], p10, 0, 0, 0);
        floatx4 p11 = __builtin_amdgcn_mfma_f32_16x16x32_bf16(GB, whiK[1], bias1[1], 0, 0, 0);
        p11 = __builtin_amdgcn_mfma_f32_16x16x32_bf16(GB, wloK[1], p11, 0, 0, 0);

        // sigma combine, packed across rows: A_i = 2^p_i + 1
        float2v A0 = {EXP2F(p00[0]), EXP2F(p10[0])};
        float2v A1 = {EXP2F(p00[1]), EXP2F(p10[1])};
        float2v A2 = {EXP2F(p00[2]), EXP2F(p10[2])};
        float2v A3 = {EXP2F(p00[3]), EXP2F(p10[3])};
        A0 += 1.0f; A1 += 1.0f; A2 += 1.0f; A3 += 1.0f;
        const float2v q01 = A0 * A1, q23 = A2 * A3;
        const float2v n4 = pkfma(q01, A2 + A3, q23 * (A0 + A1));
        const float2v d4 = q01 * q23;

        // tail channel (DPP-compacted, 1 exp per row)
        float2v At2 = {tailE(p01), tailE(p11)};
        At2 += 1.0f;

        // one reciprocal for both rows (magnitude-safe; |pre| small)
        const float2v Da = d4 * At2;
        const float inv = RCPF(Da.x * Da.y);
        const float2v inv2 = {inv * Da.y, inv * Da.x};   // {1/Da.x, 1/Da.y}
        Rm2 = pkfma(n4 * At2, inv2, Rm2);   // += sum 1/A_i  (4 main sigmas)
        Rt2 = pkfma(d4, inv2, Rt2);         // += 1/At       (tail sigma)
    }

    // unpack rows, then reduce as before
    float Rm0 = Rm2.x, Rm1 = Rm2.y, Rt0 = Rt2.x, Rt1 = Rt2.y;
    Rm0 += __shfl_xor(Rm0, 16, 64);  Rm0 += __shfl_xor(Rm0, 32, 64);
    Rm1 += __shfl_xor(Rm1, 16, 64);  Rm1 += __shfl_xor(Rm1, 32, 64);
    Rt0 += __shfl_xor(Rt0, 4, 64);   Rt0 += __shfl_xor(Rt0, 8, 64);
    Rt0 += __shfl_xor(Rt0, 16, 64);  Rt0 += __shfl_xor(Rt0, 32, 64);
    Rt1 += __shfl_xor(Rt1, 4, 64);   Rt1 += __shfl_xor(Rt1, 8, 64);
    Rt1 += __shfl_xor(Rt1, 16, 64);  Rt1 += __shfl_xor(Rt1, 32, 64);

    // folded top-MLP coefficients (channels 0..15 at c16; 16..19 at lane&3)
    const int om = c16;              // always < Ee
    const int ot = 16 + (lane & 3);  // always < Ee
    float uom = 0.0f, uot = 0.0f;
    #pragma unroll
    for (int p = 0; p < 10; ++p) {
        uom = fmaf(W2[p], W1[p * Ee + om], uom);
        uot = fmaf(W2[p], W1[p * Ee + ot], uot);
    }
    const float cfm0 = m0 * emb[zu0 * Ee + om];
    const float cfm1 = m1 * emb[zu1 * Ee + om];
    const float cft0 = m0 * emb[zu0 * Ee + ot];
    const float cft1 = m1 * emb[zu1 * Ee + ot];

    // epilogue: th = tanh(cf + m*(256 - 2R)); e = sum_o u[o]*th[o].
    // Tail terms appear 4x per 16-lane reduction group -> scale 0.25.
    float e = 0.0f;
    e = fmaf(tanhfast(cfm0 + m0 * (256.0f - 2.0f * Rm0)), uom, e);
    e = fmaf(tanhfast(cfm1 + m1 * (256.0f - 2.0f * Rm1)), uom, e);
    e = fmaf(tanhfast(cft0 + m0 * (256.0f - 2.0f * Rt0)), 0.25f * uot, e);
    e = fmaf(tanhfast(cft1 + m1 * (256.0f - 2.0f * Rt1)), 0.25f * uot, e);
    e += __shfl_xor(e, 1, 64);
    e += __shfl_xor(e, 2, 64);
    e += __shfl_xor(e, 4, 64);
    e += __shfl_xor(e, 8, 64);

    // block reduce: 4 waves -> one plain store (NO atomics)
    __shared__ float sE[4];
    if (lane == 0) sE[wave] = e;
    __syncthreads();
    if (tid == 0)
        part[blk] = sE[0] + sE[1] + sE[2] + sE[3];
}

// 64 blocks x 64 lanes: out[b] = sum of 32 block-partials + 256*C0
__global__ __launch_bounds__(64) void dtnn_reduce(
    const float* __restrict__ part,
    const float* __restrict__ b1, const float* __restrict__ W2,
    const float* __restrict__ b2, float* __restrict__ out)
{
    const int b = blockIdx.x;
    const int t = threadIdx.x;
    float v = (t < 32) ? part[b * 32 + t] : 0.0f;
    v += __shfl_xor(v, 1, 64);
    v += __shfl_xor(v, 2, 64);
    v += __shfl_xor(v, 4, 64);
    v += __shfl_xor(v, 8, 64);
    v += __shfl_xor(v, 16, 64);
    if (t == 0) {
        float c0 = b2[0];
        #pragma unroll
        for (int p = 0; p < 10; ++p) c0 = fmaf(W2[p], b1[p], c0);
        out[b] = v + 256.0f * c0 + __shfl_xor(v, 32, 64);
    }
}

extern "C" void kernel_launch(void* const* d_in, const int* in_sizes, int n_in,
                              void* d_out, int out_size, void* d_ws, size_t ws_size,
                              hipStream_t stream) {
    const int*   z    = (const int*)  d_in[0];
    const float* dist = (const float*)d_in[1];
    const float* emb  = (const float*)d_in[2];
    const float* Vw   = (const float*)d_in[3];
    const float* Vb   = (const float*)d_in[4];
    const float* W1   = (const float*)d_in[5];
    const float* b1   = (const float*)d_in[6];
    const float* W2   = (const float*)d_in[7];
    const float* b2   = (const float*)d_in[8];
    float* out = (float*)d_out;

    float* partP = (float*)d_ws;   // [NBLK]

    // 2 dispatches: fat main (2 rows/wave, self-contained) + tiny reduce
    dtnn_main<<<NBLK, 256, 0, stream>>>(z, dist, emb, Vw, Vb, W1, W2, partP);
    dtnn_reduce<<<Bsz, 64, 0, stream>>>(partP, b1, W2, b2, out);
}